// Round 18
// baseline (724.149 us; speedup 1.0000x reference)
//
#include <hip/hip_runtime.h>

typedef _Float16 f16;
typedef __attribute__((ext_vector_type(2))) __fp16 fp16x2_raw;
typedef __attribute__((ext_vector_type(4))) _Float16 f16x4;
typedef __attribute__((ext_vector_type(8))) _Float16 f16x8;
typedef __attribute__((ext_vector_type(4))) float f32x4;
typedef __attribute__((ext_vector_type(16))) float f32x16;
typedef __attribute__((ext_vector_type(2))) unsigned int u32x2;

#define NB 4
#define NS 2048
#define NE 1024
#define NH 16
#define ND 64
#define NM (NB*NS)   // 8192 tokens

__device__ __forceinline__ void gld16(const void* g, void* l) {
  __builtin_amdgcn_global_load_lds((const __attribute__((address_space(1))) unsigned int*)g,
                                   (__attribute__((address_space(3))) unsigned int*)l, 16, 0, 0);
}

// pack two f32 -> one u32 of 2 f16 (v_cvt_pkrtz_f16_f32)
__device__ __forceinline__ unsigned cvt2h(float a, float b) {
  fp16x2_raw r = __builtin_amdgcn_cvt_pkrtz(a, b);
  return __builtin_bit_cast(unsigned, r);
}

// proven (R5==R6, distinct-value operands so no reg-coalesce hazard):
// new_a[l] = l<32 ? a[l] : b[l-32]; new_b[l] = l<32 ? a[l+32] : b[l]
__device__ __forceinline__ void plswap(unsigned& a, unsigned& b) {
  asm volatile("v_permlane32_swap_b32 %0, %1" : "+v"(a), "+v"(b));
}
// NOTE: a==b plswap variant miscompiles (R9/R10 — allocator coalesces equal-valued
// operands into one VGPR). Cross-half reductions use proven __shfl_xor(x,32).

// ---------------- fused f32 -> f16 convert ----------------
__global__ __launch_bounds__(256) void cvt_all(const float* __restrict__ s0, const float* __restrict__ s1,
                                               const float* __restrict__ s2, const float* __restrict__ s3,
                                               const float* __restrict__ s4, const float* __restrict__ s5,
                                               const float* __restrict__ s6, f16* __restrict__ dst) {
  const int X = NM*NE/4;
  const int W = NE*NE/4;
  const int total = 3*X + 4*W;
  int idx = blockIdx.x * blockDim.x + threadIdx.x;
  int stride = gridDim.x * blockDim.x;
  for (int i = idx; i < total; i += stride) {
    const float* src; int off;
    if      (i <   X)     { src = s0; off = i; }
    else if (i < 2*X)     { src = s1; off = i - X; }
    else if (i < 3*X)     { src = s2; off = i - 2*X; }
    else if (i < 3*X+W)   { src = s3; off = i - 3*X; }
    else if (i < 3*X+2*W) { src = s4; off = i - (3*X+W); }
    else if (i < 3*X+3*W) { src = s5; off = i - (3*X+2*W); }
    else                  { src = s6; off = i - (3*X+3*W); }
    float4 v = ((const float4*)src)[off];
    f16x4 o;
    o[0] = (_Float16)v.x; o[1] = (_Float16)v.y; o[2] = (_Float16)v.z; o[3] = (_Float16)v.w;
    ((f16x4*)dst)[i] = o;
  }
}

// ---------------- NT GEMM: C = A[M,K] * B[N,K]^T + bias (R15-proven) ----------------
template<bool OUTF32>
__global__ __launch_bounds__(256)
void gemm_bt(const f16* __restrict__ A, const f16* __restrict__ Bw,
             const float* __restrict__ bias, float* __restrict__ Cf,
             f16* __restrict__ Ch, int M, int N, int K)
{
  __shared__ __align__(16) f16 As[128*32];
  __shared__ __align__(16) f16 Bs[128*32];
  const int t = threadIdx.x;
  const int l = t & 63, w = t >> 6;
  const int wr = w >> 1, wc = w & 1;

  // XCD swizzle: id = (xcd, slot); m_blk = (slot>>3)*8 + xcd, n_blk = slot&7 (bijective, nwg=512)
  const int id = blockIdx.x + blockIdx.y * gridDim.x;
  const int xcd = id & 7, slot = id >> 3;
  const int m0 = (((slot >> 3) << 3) | xcd) * 128;
  const int n0 = (slot & 7) * 128;

  f32x4 acc[4][4];
  #pragma unroll
  for (int i = 0; i < 4; ++i)
    #pragma unroll
    for (int j = 0; j < 4; ++j)
      acc[i][j] = f32x4{0.f, 0.f, 0.f, 0.f};

  const int off0 = (w*2+0)*1024 + l*16;
  const int off1 = (w*2+1)*1024 + l*16;
  const int row0 = off0 >> 6, k0 = (off0 & 63) >> 1;
  const int row1 = off1 >> 6, k1 = (off1 & 63) >> 1;
  const f16* a0 = A  + (size_t)(m0+row0)*K + k0;
  const f16* a1 = A  + (size_t)(m0+row1)*K + k1;
  const f16* b0 = Bw + (size_t)(n0+row0)*K + k0;
  const f16* b1 = Bw + (size_t)(n0+row1)*K + k1;
  f16* As0 = As + off0/2; f16* As1 = As + off1/2;
  f16* Bs0 = Bs + off0/2; f16* Bs1 = Bs + off1/2;

  const int aoff = (wr*64 + (l&15))*32 + ((l>>4)<<3);
  const int boff = (wc*64 + (l&15))*32 + ((l>>4)<<3);

  for (int kt = 0; kt < K; kt += 32) {
    __syncthreads();
    gld16(a0 + kt, As0);
    gld16(a1 + kt, As1);
    gld16(b0 + kt, Bs0);
    gld16(b1 + kt, Bs1);
    __syncthreads();   // compiler drains vmcnt(0) before barrier
    f16x8 af[4], bf[4];
    #pragma unroll
    for (int i = 0; i < 4; ++i) af[i] = *(const f16x8*)(As + aoff + i*512);
    #pragma unroll
    for (int j = 0; j < 4; ++j) bf[j] = *(const f16x8*)(Bs + boff + j*512);
    #pragma unroll
    for (int i = 0; i < 4; ++i)
      #pragma unroll
      for (int j = 0; j < 4; ++j)
        acc[i][j] = __builtin_amdgcn_mfma_f32_16x16x32_f16(af[i], bf[j], acc[i][j], 0, 0, 0);
  }

  #pragma unroll
  for (int j = 0; j < 4; ++j) {
    const int col = n0 + wc*64 + j*16 + (l & 15);
    const float bb = bias[col];
    #pragma unroll
    for (int i = 0; i < 4; ++i) {
      const int rowb = m0 + wr*64 + i*16 + ((l>>4)<<2);
      #pragma unroll
      for (int r = 0; r < 4; ++r) {
        float v = acc[i][j][r] + bb;
        if constexpr (OUTF32) Cf[(size_t)(rowb+r)*N + col] = v;
        else                  Ch[(size_t)(rowb+r)*N + col] = (f16)v;
      }
    }
  }
}

// ---------------- flash attention: split-key 8-wave (32 waves/CU) ----------------
// 512 thr = 2 groups x 4 waves. Group g handles keys [g*1024, (g+1)*1024), 16 iters,
// own 16KB LDS pipeline (R11-proven single-buffer loop, R15-proven arithmetic).
// Final combine: group1 writes (o,m,l) to LDS (XOR-swizzled f32), group0 merges+stores.
__global__ __launch_bounds__(512, 8)
void attn_kernel(const f16* __restrict__ Q, const f16* __restrict__ K,
                 const f16* __restrict__ V, f16* __restrict__ O)
{
  __shared__ __align__(16) f16 S_lds[16384];   // 32KB: group g tile at f16-offset g*8192
  __shared__ float m_lds[4][32];
  __shared__ float l_lds[4][32];

  const int t = threadIdx.x, l = t & 63;
  const int w6 = t >> 6;            // 0..7
  const int grp = w6 >> 2;          // 0: keys [0,1024), 1: keys [1024,2048)
  const int wg = w6 & 3;            // wave within group
  const int lq = l & 31, hi = l >> 5;

  // XCD-bijective swizzle: all 16 q-tiles of one bh on one XCD
  const int lin = blockIdx.x + (blockIdx.y << 4);
  const int xcd = lin & 7, jj = lin >> 3;
  const int bh = xcd * 8 + (jj >> 4);
  const int qt = jj & 15;
  const int b = bh >> 4, h = bh & 15;
  const size_t base = (size_t)b * NS * NE + (size_t)h * ND;
  const int q = qt*128 + wg*32 + lq;
  const int koff = grp * (NS/2);

  // Q B-fragments
  f16x8 bq[4];
  #pragma unroll
  for (int ks = 0; ks < 4; ++ks)
    bq[ks] = *(const f16x8*)&Q[base + (size_t)q*NE + ks*16 + hi*8];
  asm volatile("s_waitcnt vmcnt(0)" ::: "memory");

  f32x16 o[2];
  #pragma unroll
  for (int dt = 0; dt < 2; ++dt)
    #pragma unroll
    for (int r = 0; r < 16; ++r) o[dt][r] = 0.f;
  float m2 = -3e38f, lsum = 0.f;
  const float K2 = 0.125f * 1.44269504089f;

  // ---- K staging src (inverse-permuted; proven) ----
  const int krow0 = wg*16 + (l>>3);
  const int kgran = ((l&7) ^ (l>>3)) * 8;
  const f16* kSrc0 = K + base + (size_t)(koff + krow0)*NE + kgran;
  const f16* kSrc1 = kSrc0 + (size_t)8*NE;
  // ---- V staging src: lane = key row l, d-chunk = wg*16..+15 (proven) ----
  const f16* vSrc = V + base + (size_t)(koff + l)*NE + wg*16;

  f16* gK = &S_lds[grp*8192];
  f16* kDst0 = gK + (wg*2+0)*512 + l*8;
  f16* kDst1 = gK + (wg*2+1)*512 + l*8;
  const char* ksb = (const char*)gK;
  char* vtb = (char*)(gK + 4096);

  const size_t tileAdv = (size_t)64 * NE;

  for (int it = 0; it < 16; ++it) {
    const size_t g = (size_t)it * tileAdv;
    __syncthreads();
    gld16(kSrc0 + g, kDst0);
    gld16(kSrc1 + g, kDst1);
    {
      f16x8 va = *(const f16x8*)(vSrc + g);
      f16x8 vb = *(const f16x8*)(vSrc + g + 8);
      #pragma unroll
      for (int i = 0; i < 8; ++i) {
        const int d0 = wg*16 + i, d1 = wg*16 + 8 + i;   // d&7 == i&7 for both
        *(f16*)(vtb + ((d0*128 + l*2) ^ ((i & 7) << 4))) = va[i];
        *(f16*)(vtb + ((d1*128 + l*2) ^ ((i & 7) << 4))) = vb[i];
      }
    }
    __syncthreads();   // drains vmcnt(0) (K DMA) + lgkmcnt (V writes)

    // ---- S^T = K * Q^T ----
    f32x16 s[2];
    #pragma unroll
    for (int ct = 0; ct < 2; ++ct)
      #pragma unroll
      for (int r = 0; r < 16; ++r) s[ct][r] = 0.f;
    __builtin_amdgcn_s_setprio(1);
    #pragma unroll
    for (int ct = 0; ct < 2; ++ct) {
      const int krow = ct*32 + lq;
      const int rswz = (krow & 7) << 4;
      #pragma unroll
      for (int ks = 0; ks < 4; ++ks) {
        f16x8 ak = *(const f16x8*)(ksb + ((krow*128 + ks*32 + hi*16) ^ rswz));
        s[ct] = __builtin_amdgcn_mfma_f32_32x32x16_f16(ak, bq[ks], s[ct], 0, 0, 0);
      }
    }
    __builtin_amdgcn_s_setprio(0);

    // ---- pairwise-tree max (depth 5; exact reassociation) ----
    float mm[16];
    #pragma unroll
    for (int r = 0; r < 16; ++r) mm[r] = fmaxf(s[0][r], s[1][r]);
    #pragma unroll
    for (int st = 8; st > 0; st >>= 1)
      #pragma unroll
      for (int r = 0; r < st; ++r) mm[r] = fmaxf(mm[r], mm[r+st]);
    float mx = mm[0] * K2;
    mx = fmaxf(mx, __shfl_xor(mx, 32));

    // ---- defer-rescale (T13, THR=8 in log2) ----
    if (__any(mx > m2 + 8.0f)) {
      const float mnew = fmaxf(m2, mx);
      const float alpha = __builtin_amdgcn_exp2f(m2 - mnew);
      m2 = mnew;
      lsum *= alpha;
      #pragma unroll
      for (int dt = 0; dt < 2; ++dt)
        #pragma unroll
        for (int r = 0; r < 16; ++r) o[dt][r] *= alpha;
    }

    // ---- exp + 4-way split psum ----
    float ps4[4] = {0.f, 0.f, 0.f, 0.f};
    #pragma unroll
    for (int ct = 0; ct < 2; ++ct)
      #pragma unroll
      for (int r = 0; r < 16; ++r) {
        float p = __builtin_amdgcn_exp2f(s[ct][r]*K2 - m2);
        s[ct][r] = p;
        ps4[r & 3] += p;
      }
    lsum += (ps4[0] + ps4[1]) + (ps4[2] + ps4[3]);

    // ---- pack P, build PV B-operands via plswap (distinct values: proven) ----
    f16x8 pa[4];
    #pragma unroll
    for (int ct = 0; ct < 2; ++ct) {
      unsigned wd[8];
      #pragma unroll
      for (int m = 0; m < 4; ++m)
        #pragma unroll
        for (int hh = 0; hh < 2; ++hh)
          wd[m*2 + hh] = cvt2h(s[ct][4*m + 2*hh], s[ct][4*m + 2*hh + 1]);
      #pragma unroll
      for (int ks2 = 0; ks2 < 2; ++ks2) {
        unsigned a0 = wd[(2*ks2)*2 + 0], b0 = wd[(2*ks2+1)*2 + 0];
        unsigned a1 = wd[(2*ks2)*2 + 1], b1 = wd[(2*ks2+1)*2 + 1];
        plswap(a0, b0);
        plswap(a1, b1);
        union { unsigned u[4]; f16x8 v; } pp;
        pp.u[0] = a0; pp.u[1] = a1; pp.u[2] = b0; pp.u[3] = b1;
        pa[ct*2 + ks2] = pp.v;
      }
    }

    // ---- O^T += V^T * P ----
    __builtin_amdgcn_s_setprio(1);
    #pragma unroll
    for (int ks = 0; ks < 4; ++ks)
      #pragma unroll
      for (int dt = 0; dt < 2; ++dt) {
        const int drow = dt*32 + lq;
        f16x8 av = *(const f16x8*)(vtb + ((drow*128 + ks*32 + hi*16) ^ ((drow & 7) << 4)));
        o[dt] = __builtin_amdgcn_mfma_f32_32x32x16_f16(av, pa[ks], o[dt], 0, 0, 0);
      }
    __builtin_amdgcn_s_setprio(0);
  }

  // ================= combine the two key-halves =================
  const float lt = lsum + __shfl_xor(lsum, 32);   // full l for this lane's q over own half

  __syncthreads();   // all loop reads done before LDS is reused

  if (grp == 1) {
    // write o (f32, XOR-swizzled word index: conflict-free) and m/l
    float* ow = (float*)&S_lds[0];
    #pragma unroll
    for (int dt = 0; dt < 2; ++dt)
      #pragma unroll
      for (int k = 0; k < 16; ++k) {
        const int j = dt*16 + k;
        ow[wg*2048 + l*32 + (j ^ (l & 31))] = o[dt][k];
      }
    if (hi == 0) { m_lds[wg][lq] = m2; l_lds[wg][lq] = lt; }
  }
  __syncthreads();

  if (grp == 0) {
    const float* orp = (const float*)&S_lds[0];
    const float m_b = m_lds[wg][lq];
    const float l_b = l_lds[wg][lq];
    const float ms = fmaxf(m2, m_b);
    const float sa = __builtin_amdgcn_exp2f(m2 - ms);
    const float sb = __builtin_amdgcn_exp2f(m_b - ms);
    const float lstar = lt*sa + l_b*sb;
    const float linv = 1.0f / lstar;
    #pragma unroll
    for (int dt = 0; dt < 2; ++dt)
      #pragma unroll
      for (int m = 0; m < 4; ++m) {
        float v0 = (o[dt][4*m+0]*sa + orp[wg*2048 + l*32 + ((dt*16+4*m+0) ^ (l&31))]*sb) * linv;
        float v1 = (o[dt][4*m+1]*sa + orp[wg*2048 + l*32 + ((dt*16+4*m+1) ^ (l&31))]*sb) * linv;
        float v2 = (o[dt][4*m+2]*sa + orp[wg*2048 + l*32 + ((dt*16+4*m+2) ^ (l&31))]*sb) * linv;
        float v3 = (o[dt][4*m+3]*sa + orp[wg*2048 + l*32 + ((dt*16+4*m+3) ^ (l&31))]*sb) * linv;
        u32x2 st;
        st.x = cvt2h(v0, v1);
        st.y = cvt2h(v2, v3);
        const int d = dt*32 + 8*m + 4*hi;
        *(u32x2*)&O[base + (size_t)q*NE + d] = st;
      }
  }
}

// ---------------- launch ----------------
extern "C" void kernel_launch(void* const* d_in, const int* in_sizes, int n_in,
                              void* d_out, int out_size, void* d_ws, size_t ws_size,
                              hipStream_t stream)
{
  const float* q_in = (const float*)d_in[0];
  const float* k_in = (const float*)d_in[1];
  const float* v_in = (const float*)d_in[2];
  const float* Wq = (const float*)d_in[3];
  const float* bq = (const float*)d_in[4];
  const float* Wk = (const float*)d_in[5];
  const float* bk = (const float*)d_in[6];
  const float* Wv = (const float*)d_in[7];
  const float* bv = (const float*)d_in[8];
  const float* Wo = (const float*)d_in[9];
  const float* bo = (const float*)d_in[10];

  char* ws = (char*)d_ws;
  f16* Xq   = (f16*)(ws + 0);
  f16* Xk   = (f16*)(ws + 16777216);
  f16* Xv   = (f16*)(ws + 33554432);
  f16* Wq16 = (f16*)(ws + 50331648);
  f16* Wk16 = (f16*)(ws + 52428800);
  f16* Wv16 = (f16*)(ws + 54525952);
  f16* Wo16 = (f16*)(ws + 56623104);
  f16* Qp   = (f16*)(ws + 58720256);
  f16* Kp   = (f16*)(ws + 75497472);
  f16* Vp   = (f16*)(ws + 92274688);
  f16* Op   = (f16*)(ws + 109051904);

  cvt_all<<<2048, 256, 0, stream>>>(q_in, k_in, v_in, Wq, Wk, Wv, Wo, Xq);

  dim3 gg(8, 64);
  gemm_bt<false><<<gg, 256, 0, stream>>>(Xq, Wq16, bq, nullptr, Qp, NM, NE, NE);
  gemm_bt<false><<<gg, 256, 0, stream>>>(Xk, Wk16, bk, nullptr, Kp, NM, NE, NE);
  gemm_bt<false><<<gg, 256, 0, stream>>>(Xv, Wv16, bv, nullptr, Vp, NM, NE, NE);

  attn_kernel<<<dim3(16, 64), 512, 0, stream>>>(Qp, Kp, Vp, Op);

  gemm_bt<true><<<gg, 256, 0, stream>>>(Op, Wo16, bo, (float*)d_out, nullptr, NM, NE, NE);
}

// Round 19
// 244.580 us; speedup vs baseline: 2.9608x; 2.9608x over previous
//
#include <hip/hip_runtime.h>

typedef _Float16 f16;
typedef __attribute__((ext_vector_type(2))) __fp16 fp16x2_raw;
typedef __attribute__((ext_vector_type(4))) _Float16 f16x4;
typedef __attribute__((ext_vector_type(8))) _Float16 f16x8;
typedef __attribute__((ext_vector_type(4))) float f32x4;
typedef __attribute__((ext_vector_type(16))) float f32x16;
typedef __attribute__((ext_vector_type(2))) unsigned int u32x2;

#define NB 4
#define NS 2048
#define NE 1024
#define NH 16
#define ND 64
#define NM (NB*NS)   // 8192 tokens

__device__ __forceinline__ void gld16(const void* g, void* l) {
  __builtin_amdgcn_global_load_lds((const __attribute__((address_space(1))) unsigned int*)g,
                                   (__attribute__((address_space(3))) unsigned int*)l, 16, 0, 0);
}

// pack two f32 -> one u32 of 2 f16 (v_cvt_pkrtz_f16_f32)
__device__ __forceinline__ unsigned cvt2h(float a, float b) {
  fp16x2_raw r = __builtin_amdgcn_cvt_pkrtz(a, b);
  return __builtin_bit_cast(unsigned, r);
}

// proven (R5==R6, distinct-value operands so no reg-coalesce hazard):
// new_a[l] = l<32 ? a[l] : b[l-32]; new_b[l] = l<32 ? a[l+32] : b[l]
__device__ __forceinline__ void plswap(unsigned& a, unsigned& b) {
  asm volatile("v_permlane32_swap_b32 %0, %1" : "+v"(a), "+v"(b));
}
// NOTE: a==b plswap variant miscompiles (R9/R10 — allocator coalesces equal-valued
// operands into one VGPR). Cross-half reductions use proven __shfl_xor(x,32).

// ---------------- fused f32 -> f16 convert ----------------
__global__ __launch_bounds__(256) void cvt_all(const float* __restrict__ s0, const float* __restrict__ s1,
                                               const float* __restrict__ s2, const float* __restrict__ s3,
                                               const float* __restrict__ s4, const float* __restrict__ s5,
                                               const float* __restrict__ s6, f16* __restrict__ dst) {
  const int X = NM*NE/4;
  const int W = NE*NE/4;
  const int total = 3*X + 4*W;
  int idx = blockIdx.x * blockDim.x + threadIdx.x;
  int stride = gridDim.x * blockDim.x;
  for (int i = idx; i < total; i += stride) {
    const float* src; int off;
    if      (i <   X)     { src = s0; off = i; }
    else if (i < 2*X)     { src = s1; off = i - X; }
    else if (i < 3*X)     { src = s2; off = i - 2*X; }
    else if (i < 3*X+W)   { src = s3; off = i - 3*X; }
    else if (i < 3*X+2*W) { src = s4; off = i - (3*X+W); }
    else if (i < 3*X+3*W) { src = s5; off = i - (3*X+2*W); }
    else                  { src = s6; off = i - (3*X+3*W); }
    float4 v = ((const float4*)src)[off];
    f16x4 o;
    o[0] = (_Float16)v.x; o[1] = (_Float16)v.y; o[2] = (_Float16)v.z; o[3] = (_Float16)v.w;
    ((f16x4*)dst)[i] = o;
  }
}

// ---------------- NT GEMM: C = A[M,K] * B[N,K]^T + bias ----------------
// Single-barrier double-buffer with EXPLICIT vmcnt(0) drain before the barrier
// (R13's race hypothesis: compiler may omit the implicit drain for gld_lds DMAs,
// which have no register def-use; explicit drain makes it unconditional).
// + XCD-bijective swizzle (R15-proven).
template<bool OUTF32>
__global__ __launch_bounds__(256)
void gemm_bt(const f16* __restrict__ A, const f16* __restrict__ Bw,
             const float* __restrict__ bias, float* __restrict__ Cf,
             f16* __restrict__ Ch, int M, int N, int K)
{
  __shared__ __align__(16) f16 As[2*128*32];   // 2 x 8KB
  __shared__ __align__(16) f16 Bs[2*128*32];
  const int t = threadIdx.x;
  const int l = t & 63, w = t >> 6;
  const int wr = w >> 1, wc = w & 1;

  // XCD swizzle: id = (xcd, slot); m_blk = (slot>>3)*8 + xcd, n_blk = slot&7 (bijective, nwg=512)
  const int id = blockIdx.x + blockIdx.y * gridDim.x;
  const int xcd = id & 7, slot = id >> 3;
  const int m0 = (((slot >> 3) << 3) | xcd) * 128;
  const int n0 = (slot & 7) * 128;

  f32x4 acc[4][4];
  #pragma unroll
  for (int i = 0; i < 4; ++i)
    #pragma unroll
    for (int j = 0; j < 4; ++j)
      acc[i][j] = f32x4{0.f, 0.f, 0.f, 0.f};

  const int off0 = (w*2+0)*1024 + l*16;   // byte offsets in one 8KB tile
  const int off1 = (w*2+1)*1024 + l*16;
  const int row0 = off0 >> 6, k0 = (off0 & 63) >> 1;
  const int row1 = off1 >> 6, k1 = (off1 & 63) >> 1;
  const f16* a0 = A  + (size_t)(m0+row0)*K + k0;
  const f16* a1 = A  + (size_t)(m0+row1)*K + k1;
  const f16* b0 = Bw + (size_t)(n0+row0)*K + k0;
  const f16* b1 = Bw + (size_t)(n0+row1)*K + k1;

  const int aoff = (wr*64 + (l&15))*32 + ((l>>4)<<3);
  const int boff = (wc*64 + (l&15))*32 + ((l>>4)<<3);

  // prologue: stage K-step 0 into buf 0
  gld16(a0, As + off0/2);
  gld16(a1, As + off1/2);
  gld16(b0, Bs + off0/2);
  gld16(b1, Bs + off1/2);
  asm volatile("s_waitcnt vmcnt(0)" ::: "memory");
  __syncthreads();

  const int NK = K / 32;
  for (int ksi = 0; ksi < NK; ++ksi) {
    const int cur = ksi & 1, nxt = cur ^ 1;
    if (ksi < NK-1) {
      const int kt = (ksi+1) * 32;
      gld16(a0 + kt, As + nxt*4096 + off0/2);
      gld16(a1 + kt, As + nxt*4096 + off1/2);
      gld16(b0 + kt, Bs + nxt*4096 + off0/2);
      gld16(b1 + kt, Bs + nxt*4096 + off1/2);
    }
    const f16* Ac = As + cur*4096;
    const f16* Bc = Bs + cur*4096;
    f16x8 af[4], bf[4];
    #pragma unroll
    for (int i = 0; i < 4; ++i) af[i] = *(const f16x8*)(Ac + aoff + i*512);
    #pragma unroll
    for (int j = 0; j < 4; ++j) bf[j] = *(const f16x8*)(Bc + boff + j*512);
    #pragma unroll
    for (int i = 0; i < 4; ++i)
      #pragma unroll
      for (int j = 0; j < 4; ++j)
        acc[i][j] = __builtin_amdgcn_mfma_f32_16x16x32_f16(af[i], bf[j], acc[i][j], 0, 0, 0);
    // explicit unconditional drain of this iter's DMAs, then one barrier
    asm volatile("s_waitcnt vmcnt(0)" ::: "memory");
    __syncthreads();
  }

  #pragma unroll
  for (int j = 0; j < 4; ++j) {
    const int col = n0 + wc*64 + j*16 + (l & 15);
    const float bb = bias[col];
    #pragma unroll
    for (int i = 0; i < 4; ++i) {
      const int rowb = m0 + wr*64 + i*16 + ((l>>4)<<2);
      #pragma unroll
      for (int r = 0; r < 4; ++r) {
        float v = acc[i][j][r] + bb;
        if constexpr (OUTF32) Cf[(size_t)(rowb+r)*N + col] = v;
        else                  Ch[(size_t)(rowb+r)*N + col] = (f16)v;
      }
    }
  }
}

// ---------------- flash attention: R15-proven (dbuf + tree-max + split psum + defer-rescale) ----------------
__global__ __launch_bounds__(256, 4)
void attn_kernel(const f16* __restrict__ Q, const f16* __restrict__ K,
                 const f16* __restrict__ V, f16* __restrict__ O)
{
  __shared__ __align__(16) f16 S_lds[16384];

  const int t = threadIdx.x, l = t & 63, w = t >> 6;
  const int lq = l & 31, hi = l >> 5;

  // XCD-bijective swizzle: all 16 q-tiles of one bh on one XCD
  const int lin = blockIdx.x + (blockIdx.y << 4);
  const int xcd = lin & 7, jj = lin >> 3;
  const int bh = xcd * 8 + (jj >> 4);
  const int qt = jj & 15;
  const int b = bh >> 4, h = bh & 15;
  const size_t base = (size_t)b * NS * NE + (size_t)h * ND;
  const int q = qt*128 + w*32 + lq;

  // Q B-fragments
  f16x8 bq[4];
  #pragma unroll
  for (int ks = 0; ks < 4; ++ks)
    bq[ks] = *(const f16x8*)&Q[base + (size_t)q*NE + ks*16 + hi*8];
  asm volatile("s_waitcnt vmcnt(0)" ::: "memory");

  f32x16 o[2];
  #pragma unroll
  for (int dt = 0; dt < 2; ++dt)
    #pragma unroll
    for (int r = 0; r < 16; ++r) o[dt][r] = 0.f;
  float m2 = -3e38f, lsum = 0.f;
  const float K2 = 0.125f * 1.44269504089f;

  // ---- K staging src (inverse-permuted; proven) ----
  const int krow0 = w*16 + (l>>3);
  const int kgran = ((l&7) ^ (l>>3)) * 8;
  const f16* kSrc0 = K + base + (size_t)krow0*NE + kgran;
  const f16* kSrc1 = kSrc0 + (size_t)8*NE;
  // ---- V staging src: lane = key row l, d-chunk = w*16..w*16+15 (proven) ----
  const f16* vSrc = V + base + (size_t)l*NE + w*16;

  const size_t tileAdv = (size_t)64 * NE;
  const int kd0 = (w*2+0)*512 + l*8;
  const int kd1 = (w*2+1)*512 + l*8;

  // ================= prologue: stage tile 0 into buf 0 =================
  f16x8 va, vb;
  {
    gld16(kSrc0, &S_lds[0] + kd0);
    gld16(kSrc1, &S_lds[0] + kd1);
    va = *(const f16x8*)(vSrc);
    vb = *(const f16x8*)(vSrc + 8);
    asm volatile("s_waitcnt vmcnt(0)" ::: "memory");
    char* vt0 = (char*)&S_lds[4096];
    #pragma unroll
    for (int i = 0; i < 8; ++i) {
      const int d0 = w*16 + i, d1 = w*16 + 8 + i;   // d&7 == i&7 for both
      *(f16*)(vt0 + ((d0*128 + l*2) ^ ((i & 7) << 4))) = va[i];
      *(f16*)(vt0 + ((d1*128 + l*2) ^ ((i & 7) << 4))) = vb[i];
    }
  }
  __syncthreads();

  for (int it = 0; it < 32; ++it) {
    const int cur = it & 1, nb = cur ^ 1;
    const char* ksb = (const char*)(&S_lds[cur*8192]);
    const char* vtb = (const char*)(&S_lds[cur*8192 + 4096]);

    // ---- issue next-tile staging loads (overlap with this tile's compute) ----
    if (it < 31) {
      const size_t g = (size_t)(it+1) * tileAdv;
      gld16(kSrc0 + g, &S_lds[nb*8192] + kd0);
      gld16(kSrc1 + g, &S_lds[nb*8192] + kd1);
      va = *(const f16x8*)(vSrc + g);
      vb = *(const f16x8*)(vSrc + g + 8);
    }

    // ---- S^T = K * Q^T ----
    f32x16 s[2];
    #pragma unroll
    for (int ct = 0; ct < 2; ++ct)
      #pragma unroll
      for (int r = 0; r < 16; ++r) s[ct][r] = 0.f;
    __builtin_amdgcn_s_setprio(1);
    #pragma unroll
    for (int ct = 0; ct < 2; ++ct) {
      const int krow = ct*32 + lq;
      const int rswz = (krow & 7) << 4;
      #pragma unroll
      for (int ks = 0; ks < 4; ++ks) {
        f16x8 ak = *(const f16x8*)(ksb + ((krow*128 + ks*32 + hi*16) ^ rswz));
        s[ct] = __builtin_amdgcn_mfma_f32_32x32x16_f16(ak, bq[ks], s[ct], 0, 0, 0);
      }
    }
    __builtin_amdgcn_s_setprio(0);

    // ---- pairwise-tree max (depth 5; exact reassociation) ----
    float mm[16];
    #pragma unroll
    for (int r = 0; r < 16; ++r) mm[r] = fmaxf(s[0][r], s[1][r]);
    #pragma unroll
    for (int st = 8; st > 0; st >>= 1)
      #pragma unroll
      for (int r = 0; r < st; ++r) mm[r] = fmaxf(mm[r], mm[r+st]);
    float mx = mm[0] * K2;
    mx = fmaxf(mx, __shfl_xor(mx, 32));

    // ---- defer-rescale (T13, THR=8 in log2) ----
    if (__any(mx > m2 + 8.0f)) {
      const float mnew = fmaxf(m2, mx);
      const float alpha = __builtin_amdgcn_exp2f(m2 - mnew);
      m2 = mnew;
      lsum *= alpha;
      #pragma unroll
      for (int dt = 0; dt < 2; ++dt)
        #pragma unroll
        for (int r = 0; r < 16; ++r) o[dt][r] *= alpha;
    }

    // ---- exp + 4-way split psum ----
    float ps4[4] = {0.f, 0.f, 0.f, 0.f};
    #pragma unroll
    for (int ct = 0; ct < 2; ++ct)
      #pragma unroll
      for (int r = 0; r < 16; ++r) {
        float p = __builtin_amdgcn_exp2f(s[ct][r]*K2 - m2);
        s[ct][r] = p;
        ps4[r & 3] += p;
      }
    lsum += (ps4[0] + ps4[1]) + (ps4[2] + ps4[3]);

    // ---- pack P, build PV B-operands via plswap (distinct values: proven) ----
    f16x8 pa[4];
    #pragma unroll
    for (int ct = 0; ct < 2; ++ct) {
      unsigned wd[8];
      #pragma unroll
      for (int m = 0; m < 4; ++m)
        #pragma unroll
        for (int hh = 0; hh < 2; ++hh)
          wd[m*2 + hh] = cvt2h(s[ct][4*m + 2*hh], s[ct][4*m + 2*hh + 1]);
      #pragma unroll
      for (int ks2 = 0; ks2 < 2; ++ks2) {
        unsigned a0 = wd[(2*ks2)*2 + 0], b0 = wd[(2*ks2+1)*2 + 0];
        unsigned a1 = wd[(2*ks2)*2 + 1], b1 = wd[(2*ks2+1)*2 + 1];
        plswap(a0, b0);
        plswap(a1, b1);
        union { unsigned u[4]; f16x8 v; } pp;
        pp.u[0] = a0; pp.u[1] = a1; pp.u[2] = b0; pp.u[3] = b1;
        pa[ct*2 + ks2] = pp.v;
      }
    }

    // ---- O^T += V^T * P ----
    __builtin_amdgcn_s_setprio(1);
    #pragma unroll
    for (int ks = 0; ks < 4; ++ks)
      #pragma unroll
      for (int dt = 0; dt < 2; ++dt) {
        const int drow = dt*32 + lq;
        f16x8 av = *(const f16x8*)(vtb + ((drow*128 + ks*32 + hi*16) ^ ((drow & 7) << 4)));
        o[dt] = __builtin_amdgcn_mfma_f32_32x32x16_f16(av, pa[ks], o[dt], 0, 0, 0);
      }
    __builtin_amdgcn_s_setprio(0);

    // ---- finish staging next tile: drain loads, write Vt, single barrier ----
    if (it < 31) {
      asm volatile("s_waitcnt vmcnt(0)" ::: "memory");
      char* vtn = (char*)(&S_lds[nb*8192 + 4096]);
      #pragma unroll
      for (int i = 0; i < 8; ++i) {
        const int d0 = w*16 + i, d1 = w*16 + 8 + i;
        *(f16*)(vtn + ((d0*128 + l*2) ^ ((i & 7) << 4))) = va[i];
        *(f16*)(vtn + ((d1*128 + l*2) ^ ((i & 7) << 4))) = vb[i];
      }
      __syncthreads();
    }
  }

  // ---- epilogue: cross-half lsum combine (shfl, proven), normalize, store ----
  const float lt = lsum + __shfl_xor(lsum, 32);
  const float linv = 1.0f / lt;
  #pragma unroll
  for (int dt = 0; dt < 2; ++dt)
    #pragma unroll
    for (int m = 0; m < 4; ++m) {
      u32x2 st;
      st.x = cvt2h(o[dt][4*m+0]*linv, o[dt][4*m+1]*linv);
      st.y = cvt2h(o[dt][4*m+2]*linv, o[dt][4*m+3]*linv);
      const int d = dt*32 + 8*m + 4*hi;
      *(u32x2*)&O[base + (size_t)q*NE + d] = st;
    }
}

// ---------------- launch ----------------
extern "C" void kernel_launch(void* const* d_in, const int* in_sizes, int n_in,
                              void* d_out, int out_size, void* d_ws, size_t ws_size,
                              hipStream_t stream)
{
  const float* q_in = (const float*)d_in[0];
  const float* k_in = (const float*)d_in[1];
  const float* v_in = (const float*)d_in[2];
  const float* Wq = (const float*)d_in[3];
  const float* bq = (const float*)d_in[4];
  const float* Wk = (const float*)d_in[5];
  const float* bk = (const float*)d_in[6];
  const float* Wv = (const float*)d_in[7];
  const float* bv = (const float*)d_in[8];
  const float* Wo = (const float*)d_in[9];
  const float* bo = (const float*)d_in[10];

  char* ws = (char*)d_ws;
  f16* Xq   = (f16*)(ws + 0);
  f16* Xk   = (f16*)(ws + 16777216);
  f16* Xv   = (f16*)(ws + 33554432);
  f16* Wq16 = (f16*)(ws + 50331648);
  f16* Wk16 = (f16*)(ws + 52428800);
  f16* Wv16 = (f16*)(ws + 54525952);
  f16* Wo16 = (f16*)(ws + 56623104);
  f16* Qp   = (f16*)(ws + 58720256);
  f16* Kp   = (f16*)(ws + 75497472);
  f16* Vp   = (f16*)(ws + 92274688);
  f16* Op   = (f16*)(ws + 109051904);

  cvt_all<<<2048, 256, 0, stream>>>(q_in, k_in, v_in, Wq, Wk, Wv, Wo, Xq);

  dim3 gg(8, 64);
  gemm_bt<false><<<gg, 256, 0, stream>>>(Xq, Wq16, bq, nullptr, Qp, NM, NE, NE);
  gemm_bt<false><<<gg, 256, 0, stream>>>(Xk, Wk16, bk, nullptr, Kp, NM, NE, NE);
  gemm_bt<false><<<gg, 256, 0, stream>>>(Xv, Wv16, bv, nullptr, Vp, NM, NE, NE);

  attn_kernel<<<dim3(16, 64), 256, 0, stream>>>(Qp, Kp, Vp, Op);

  gemm_bt<true><<<gg, 256, 0, stream>>>(Op, Wo16, bo, (float*)d_out, nullptr, NM, NE, NE);
}

// Round 20
// 238.930 us; speedup vs baseline: 3.0308x; 1.0236x over previous
//
#include <hip/hip_runtime.h>

typedef _Float16 f16;
typedef __attribute__((ext_vector_type(2))) __fp16 fp16x2_raw;
typedef __attribute__((ext_vector_type(4))) _Float16 f16x4;
typedef __attribute__((ext_vector_type(8))) _Float16 f16x8;
typedef __attribute__((ext_vector_type(4))) float f32x4;
typedef __attribute__((ext_vector_type(16))) float f32x16;
typedef __attribute__((ext_vector_type(2))) unsigned int u32x2;
typedef __attribute__((ext_vector_type(4))) unsigned int u32x4;

#define NB 4
#define NS 2048
#define NE 1024
#define NH 16
#define ND 64
#define NM (NB*NS)   // 8192 tokens

__device__ __forceinline__ void gld16(const void* g, void* l) {
  __builtin_amdgcn_global_load_lds((const __attribute__((address_space(1))) unsigned int*)g,
                                   (__attribute__((address_space(3))) unsigned int*)l, 16, 0, 0);
}

// pack two f32 -> one u32 of 2 f16 (v_cvt_pkrtz_f16_f32)
__device__ __forceinline__ unsigned cvt2h(float a, float b) {
  fp16x2_raw r = __builtin_amdgcn_cvt_pkrtz(a, b);
  return __builtin_bit_cast(unsigned, r);
}

// proven (R5==R6, distinct-value operands so no reg-coalesce hazard):
// new_a[l] = l<32 ? a[l] : b[l-32]; new_b[l] = l<32 ? a[l+32] : b[l]
__device__ __forceinline__ void plswap(unsigned& a, unsigned& b) {
  asm volatile("v_permlane32_swap_b32 %0, %1" : "+v"(a), "+v"(b));
}
// NOTE: a==b plswap variant miscompiles (R9/R10 — allocator coalesces equal-valued
// operands into one VGPR). Cross-half reductions use proven __shfl_xor(x,32).

// ---------------- f32 -> f16 convert, WEIGHTS ONLY (12 MB traffic, ~2 us) ----------------
__global__ __launch_bounds__(256) void cvt_w(const float* __restrict__ s3, const float* __restrict__ s4,
                                             const float* __restrict__ s5, const float* __restrict__ s6,
                                             f16* __restrict__ dst) {
  const int W = NE*NE/4;       // float4s per weight
  const int total = 4*W;
  int idx = blockIdx.x * blockDim.x + threadIdx.x;
  int stride = gridDim.x * blockDim.x;
  for (int i = idx; i < total; i += stride) {
    const float* src; int off;
    if      (i <   W)   { src = s3; off = i; }
    else if (i < 2*W)   { src = s4; off = i - W; }
    else if (i < 3*W)   { src = s5; off = i - 2*W; }
    else                { src = s6; off = i - 3*W; }
    float4 v = ((const float4*)src)[off];
    f16x4 o;
    o[0] = (_Float16)v.x; o[1] = (_Float16)v.y; o[2] = (_Float16)v.z; o[3] = (_Float16)v.w;
    ((f16x4*)dst)[i] = o;
  }
}

// ---------------- NT GEMM: C = A * B^T + bias ----------------
// R19-proven single-barrier dbuf with explicit vmcnt(0) drain + XCD-bijective swizzle.
// AF32: A is f32 in global; staged via reg-load + cvt_pkrtz + ds_write_b128 (fused convert).
template<bool AF32, bool OUTF32>
__global__ __launch_bounds__(256)
void gemm_bt(const void* __restrict__ Asrc, const f16* __restrict__ Bw,
             const float* __restrict__ bias, float* __restrict__ Cf,
             f16* __restrict__ Ch, int M, int N, int K)
{
  __shared__ __align__(16) f16 As[2*128*32];   // 2 x 8KB
  __shared__ __align__(16) f16 Bs[2*128*32];
  const int t = threadIdx.x;
  const int l = t & 63, w = t >> 6;
  const int wr = w >> 1, wc = w & 1;

  // XCD swizzle: id = (xcd, slot); m_blk = (slot>>3)*8 + xcd, n_blk = slot&7 (bijective, nwg=512)
  const int id = blockIdx.x + blockIdx.y * gridDim.x;
  const int xcd = id & 7, slot = id >> 3;
  const int m0 = (((slot >> 3) << 3) | xcd) * 128;
  const int n0 = (slot & 7) * 128;

  f32x4 acc[4][4];
  #pragma unroll
  for (int i = 0; i < 4; ++i)
    #pragma unroll
    for (int j = 0; j < 4; ++j)
      acc[i][j] = f32x4{0.f, 0.f, 0.f, 0.f};

  const int off0 = (w*2+0)*1024 + l*16;   // byte offsets in one 8KB tile
  const int off1 = (w*2+1)*1024 + l*16;
  const int row0 = off0 >> 6, k0 = (off0 & 63) >> 1;
  const int row1 = off1 >> 6, k1 = (off1 & 63) >> 1;
  const f16*   a0h = (const f16*)Asrc   + (size_t)(m0+row0)*K + k0;
  const f16*   a1h = (const f16*)Asrc   + (size_t)(m0+row1)*K + k1;
  const float* a0f = (const float*)Asrc + (size_t)(m0+row0)*K + k0;
  const float* a1f = (const float*)Asrc + (size_t)(m0+row1)*K + k1;
  const f16* b0 = Bw + (size_t)(n0+row0)*K + k0;
  const f16* b1 = Bw + (size_t)(n0+row1)*K + k1;

  const int aoff = (wr*64 + (l&15))*32 + ((l>>4)<<3);
  const int boff = (wc*64 + (l&15))*32 + ((l>>4)<<3);

  // prologue: stage K-step 0 into buf 0
  gld16(b0, Bs + off0/2);
  gld16(b1, Bs + off1/2);
  if constexpr (AF32) {
    float4 x0 = *(const float4*)(a0f);
    float4 x1 = *(const float4*)(a0f + 4);
    float4 y0 = *(const float4*)(a1f);
    float4 y1 = *(const float4*)(a1f + 4);
    u32x4 wa, wb;
    wa[0] = cvt2h(x0.x, x0.y); wa[1] = cvt2h(x0.z, x0.w);
    wa[2] = cvt2h(x1.x, x1.y); wa[3] = cvt2h(x1.z, x1.w);
    wb[0] = cvt2h(y0.x, y0.y); wb[1] = cvt2h(y0.z, y0.w);
    wb[2] = cvt2h(y1.x, y1.y); wb[3] = cvt2h(y1.z, y1.w);
    *(u32x4*)(As + off0/2) = wa;
    *(u32x4*)(As + off1/2) = wb;
  } else {
    gld16(a0h, As + off0/2);
    gld16(a1h, As + off1/2);
  }
  asm volatile("s_waitcnt vmcnt(0)" ::: "memory");
  __syncthreads();

  const int NK = K / 32;
  for (int ksi = 0; ksi < NK; ++ksi) {
    const int cur = ksi & 1, nxt = cur ^ 1;
    float4 x0, x1, y0, y1;
    if (ksi < NK-1) {
      const int kt = (ksi+1) * 32;
      gld16(b0 + kt, Bs + nxt*4096 + off0/2);
      gld16(b1 + kt, Bs + nxt*4096 + off1/2);
      if constexpr (AF32) {
        x0 = *(const float4*)(a0f + kt);
        x1 = *(const float4*)(a0f + kt + 4);
        y0 = *(const float4*)(a1f + kt);
        y1 = *(const float4*)(a1f + kt + 4);
      } else {
        gld16(a0h + kt, As + nxt*4096 + off0/2);
        gld16(a1h + kt, As + nxt*4096 + off1/2);
      }
    }
    const f16* Ac = As + cur*4096;
    const f16* Bc = Bs + cur*4096;
    f16x8 af[4], bf[4];
    #pragma unroll
    for (int i = 0; i < 4; ++i) af[i] = *(const f16x8*)(Ac + aoff + i*512);
    #pragma unroll
    for (int j = 0; j < 4; ++j) bf[j] = *(const f16x8*)(Bc + boff + j*512);
    #pragma unroll
    for (int i = 0; i < 4; ++i)
      #pragma unroll
      for (int j = 0; j < 4; ++j)
        acc[i][j] = __builtin_amdgcn_mfma_f32_16x16x32_f16(af[i], bf[j], acc[i][j], 0, 0, 0);
    // explicit unconditional drain of this iter's DMAs/loads
    asm volatile("s_waitcnt vmcnt(0)" ::: "memory");
    if constexpr (AF32) {
      if (ksi < NK-1) {
        u32x4 wa, wb;
        wa[0] = cvt2h(x0.x, x0.y); wa[1] = cvt2h(x0.z, x0.w);
        wa[2] = cvt2h(x1.x, x1.y); wa[3] = cvt2h(x1.z, x1.w);
        wb[0] = cvt2h(y0.x, y0.y); wb[1] = cvt2h(y0.z, y0.w);
        wb[2] = cvt2h(y1.x, y1.y); wb[3] = cvt2h(y1.z, y1.w);
        *(u32x4*)(As + nxt*4096 + off0/2) = wa;
        *(u32x4*)(As + nxt*4096 + off1/2) = wb;
      }
    }
    __syncthreads();
  }

  #pragma unroll
  for (int j = 0; j < 4; ++j) {
    const int col = n0 + wc*64 + j*16 + (l & 15);
    const float bb = bias[col];
    #pragma unroll
    for (int i = 0; i < 4; ++i) {
      const int rowb = m0 + wr*64 + i*16 + ((l>>4)<<2);
      #pragma unroll
      for (int r = 0; r < 4; ++r) {
        float v = acc[i][j][r] + bb;
        if constexpr (OUTF32) Cf[(size_t)(rowb+r)*N + col] = v;
        else                  Ch[(size_t)(rowb+r)*N + col] = (f16)v;
      }
    }
  }
}

// ---------------- flash attention: R15-proven (dbuf + tree-max + split psum + defer-rescale) ----------------
__global__ __launch_bounds__(256, 4)
void attn_kernel(const f16* __restrict__ Q, const f16* __restrict__ K,
                 const f16* __restrict__ V, f16* __restrict__ O)
{
  __shared__ __align__(16) f16 S_lds[16384];

  const int t = threadIdx.x, l = t & 63, w = t >> 6;
  const int lq = l & 31, hi = l >> 5;

  // XCD-bijective swizzle: all 16 q-tiles of one bh on one XCD
  const int lin = blockIdx.x + (blockIdx.y << 4);
  const int xcd = lin & 7, jj = lin >> 3;
  const int bh = xcd * 8 + (jj >> 4);
  const int qt = jj & 15;
  const int b = bh >> 4, h = bh & 15;
  const size_t base = (size_t)b * NS * NE + (size_t)h * ND;
  const int q = qt*128 + w*32 + lq;

  // Q B-fragments
  f16x8 bq[4];
  #pragma unroll
  for (int ks = 0; ks < 4; ++ks)
    bq[ks] = *(const f16x8*)&Q[base + (size_t)q*NE + ks*16 + hi*8];
  asm volatile("s_waitcnt vmcnt(0)" ::: "memory");

  f32x16 o[2];
  #pragma unroll
  for (int dt = 0; dt < 2; ++dt)
    #pragma unroll
    for (int r = 0; r < 16; ++r) o[dt][r] = 0.f;
  float m2 = -3e38f, lsum = 0.f;
  const float K2 = 0.125f * 1.44269504089f;

  // ---- K staging src (inverse-permuted; proven) ----
  const int krow0 = w*16 + (l>>3);
  const int kgran = ((l&7) ^ (l>>3)) * 8;
  const f16* kSrc0 = K + base + (size_t)krow0*NE + kgran;
  const f16* kSrc1 = kSrc0 + (size_t)8*NE;
  // ---- V staging src: lane = key row l, d-chunk = w*16..w*16+15 (proven) ----
  const f16* vSrc = V + base + (size_t)l*NE + w*16;

  const size_t tileAdv = (size_t)64 * NE;
  const int kd0 = (w*2+0)*512 + l*8;
  const int kd1 = (w*2+1)*512 + l*8;

  // ================= prologue: stage tile 0 into buf 0 =================
  f16x8 va, vb;
  {
    gld16(kSrc0, &S_lds[0] + kd0);
    gld16(kSrc1, &S_lds[0] + kd1);
    va = *(const f16x8*)(vSrc);
    vb = *(const f16x8*)(vSrc + 8);
    asm volatile("s_waitcnt vmcnt(0)" ::: "memory");
    char* vt0 = (char*)&S_lds[4096];
    #pragma unroll
    for (int i = 0; i < 8; ++i) {
      const int d0 = w*16 + i, d1 = w*16 + 8 + i;   // d&7 == i&7 for both
      *(f16*)(vt0 + ((d0*128 + l*2) ^ ((i & 7) << 4))) = va[i];
      *(f16*)(vt0 + ((d1*128 + l*2) ^ ((i & 7) << 4))) = vb[i];
    }
  }
  __syncthreads();

  for (int it = 0; it < 32; ++it) {
    const int cur = it & 1, nb = cur ^ 1;
    const char* ksb = (const char*)(&S_lds[cur*8192]);
    const char* vtb = (const char*)(&S_lds[cur*8192 + 4096]);

    // ---- issue next-tile staging loads (overlap with this tile's compute) ----
    if (it < 31) {
      const size_t g = (size_t)(it+1) * tileAdv;
      gld16(kSrc0 + g, &S_lds[nb*8192] + kd0);
      gld16(kSrc1 + g, &S_lds[nb*8192] + kd1);
      va = *(const f16x8*)(vSrc + g);
      vb = *(const f16x8*)(vSrc + g + 8);
    }

    // ---- S^T = K * Q^T ----
    f32x16 s[2];
    #pragma unroll
    for (int ct = 0; ct < 2; ++ct)
      #pragma unroll
      for (int r = 0; r < 16; ++r) s[ct][r] = 0.f;
    __builtin_amdgcn_s_setprio(1);
    #pragma unroll
    for (int ct = 0; ct < 2; ++ct) {
      const int krow = ct*32 + lq;
      const int rswz = (krow & 7) << 4;
      #pragma unroll
      for (int ks = 0; ks < 4; ++ks) {
        f16x8 ak = *(const f16x8*)(ksb + ((krow*128 + ks*32 + hi*16) ^ rswz));
        s[ct] = __builtin_amdgcn_mfma_f32_32x32x16_f16(ak, bq[ks], s[ct], 0, 0, 0);
      }
    }
    __builtin_amdgcn_s_setprio(0);

    // ---- pairwise-tree max (depth 5; exact reassociation) ----
    float mm[16];
    #pragma unroll
    for (int r = 0; r < 16; ++r) mm[r] = fmaxf(s[0][r], s[1][r]);
    #pragma unroll
    for (int st = 8; st > 0; st >>= 1)
      #pragma unroll
      for (int r = 0; r < st; ++r) mm[r] = fmaxf(mm[r], mm[r+st]);
    float mx = mm[0] * K2;
    mx = fmaxf(mx, __shfl_xor(mx, 32));

    // ---- defer-rescale (T13, THR=8 in log2) ----
    if (__any(mx > m2 + 8.0f)) {
      const float mnew = fmaxf(m2, mx);
      const float alpha = __builtin_amdgcn_exp2f(m2 - mnew);
      m2 = mnew;
      lsum *= alpha;
      #pragma unroll
      for (int dt = 0; dt < 2; ++dt)
        #pragma unroll
        for (int r = 0; r < 16; ++r) o[dt][r] *= alpha;
    }

    // ---- exp + 4-way split psum ----
    float ps4[4] = {0.f, 0.f, 0.f, 0.f};
    #pragma unroll
    for (int ct = 0; ct < 2; ++ct)
      #pragma unroll
      for (int r = 0; r < 16; ++r) {
        float p = __builtin_amdgcn_exp2f(s[ct][r]*K2 - m2);
        s[ct][r] = p;
        ps4[r & 3] += p;
      }
    lsum += (ps4[0] + ps4[1]) + (ps4[2] + ps4[3]);

    // ---- pack P, build PV B-operands via plswap (distinct values: proven) ----
    f16x8 pa[4];
    #pragma unroll
    for (int ct = 0; ct < 2; ++ct) {
      unsigned wd[8];
      #pragma unroll
      for (int m = 0; m < 4; ++m)
        #pragma unroll
        for (int hh = 0; hh < 2; ++hh)
          wd[m*2 + hh] = cvt2h(s[ct][4*m + 2*hh], s[ct][4*m + 2*hh + 1]);
      #pragma unroll
      for (int ks2 = 0; ks2 < 2; ++ks2) {
        unsigned a0 = wd[(2*ks2)*2 + 0], b0 = wd[(2*ks2+1)*2 + 0];
        unsigned a1 = wd[(2*ks2)*2 + 1], b1 = wd[(2*ks2+1)*2 + 1];
        plswap(a0, b0);
        plswap(a1, b1);
        union { unsigned u[4]; f16x8 v; } pp;
        pp.u[0] = a0; pp.u[1] = a1; pp.u[2] = b0; pp.u[3] = b1;
        pa[ct*2 + ks2] = pp.v;
      }
    }

    // ---- O^T += V^T * P ----
    __builtin_amdgcn_s_setprio(1);
    #pragma unroll
    for (int ks = 0; ks < 4; ++ks)
      #pragma unroll
      for (int dt = 0; dt < 2; ++dt) {
        const int drow = dt*32 + lq;
        f16x8 av = *(const f16x8*)(vtb + ((drow*128 + ks*32 + hi*16) ^ ((drow & 7) << 4)));
        o[dt] = __builtin_amdgcn_mfma_f32_32x32x16_f16(av, pa[ks], o[dt], 0, 0, 0);
      }
    __builtin_amdgcn_s_setprio(0);

    // ---- finish staging next tile: drain loads, write Vt, single barrier ----
    if (it < 31) {
      asm volatile("s_waitcnt vmcnt(0)" ::: "memory");
      char* vtn = (char*)(&S_lds[nb*8192 + 4096]);
      #pragma unroll
      for (int i = 0; i < 8; ++i) {
        const int d0 = w*16 + i, d1 = w*16 + 8 + i;
        *(f16*)(vtn + ((d0*128 + l*2) ^ ((i & 7) << 4))) = va[i];
        *(f16*)(vtn + ((d1*128 + l*2) ^ ((i & 7) << 4))) = vb[i];
      }
      __syncthreads();
    }
  }

  // ---- epilogue: cross-half lsum combine (shfl, proven), normalize, store ----
  const float lt = lsum + __shfl_xor(lsum, 32);
  const float linv = 1.0f / lt;
  #pragma unroll
  for (int dt = 0; dt < 2; ++dt)
    #pragma unroll
    for (int m = 0; m < 4; ++m) {
      u32x2 st;
      st.x = cvt2h(o[dt][4*m+0]*linv, o[dt][4*m+1]*linv);
      st.y = cvt2h(o[dt][4*m+2]*linv, o[dt][4*m+3]*linv);
      const int d = dt*32 + 8*m + 4*hi;
      *(u32x2*)&O[base + (size_t)q*NE + d] = st;
    }
}

// ---------------- launch ----------------
extern "C" void kernel_launch(void* const* d_in, const int* in_sizes, int n_in,
                              void* d_out, int out_size, void* d_ws, size_t ws_size,
                              hipStream_t stream)
{
  const float* q_in = (const float*)d_in[0];
  const float* k_in = (const float*)d_in[1];
  const float* v_in = (const float*)d_in[2];
  const float* Wq = (const float*)d_in[3];
  const float* bq = (const float*)d_in[4];
  const float* Wk = (const float*)d_in[5];
  const float* bk = (const float*)d_in[6];
  const float* Wv = (const float*)d_in[7];
  const float* bv = (const float*)d_in[8];
  const float* Wo = (const float*)d_in[9];
  const float* bo = (const float*)d_in[10];

  char* ws = (char*)d_ws;
  f16* Wq16 = (f16*)(ws + 50331648);   // 4 weights contiguous, 2MB each
  f16* Wk16 = (f16*)(ws + 52428800);
  f16* Wv16 = (f16*)(ws + 54525952);
  f16* Wo16 = (f16*)(ws + 56623104);
  f16* Qp   = (f16*)(ws + 58720256);
  f16* Kp   = (f16*)(ws + 75497472);
  f16* Vp   = (f16*)(ws + 92274688);
  f16* Op   = (f16*)(ws + 109051904);

  cvt_w<<<1024, 256, 0, stream>>>(Wq, Wk, Wv, Wo, Wq16);

  dim3 gg(8, 64);
  gemm_bt<true,  false><<<gg, 256, 0, stream>>>(q_in, Wq16, bq, nullptr, Qp, NM, NE, NE);
  gemm_bt<true,  false><<<gg, 256, 0, stream>>>(k_in, Wk16, bk, nullptr, Kp, NM, NE, NE);
  gemm_bt<true,  false><<<gg, 256, 0, stream>>>(v_in, Wv16, bv, nullptr, Vp, NM, NE, NE);

  attn_kernel<<<dim3(16, 64), 256, 0, stream>>>(Qp, Kp, Vp, Op);

  gemm_bt<false, true><<<gg, 256, 0, stream>>>(Op, Wo16, bo, (float*)d_out, nullptr, NM, NE, NE);
}